// Round 8
// baseline (323.587 us; speedup 1.0000x reference)
//
#include <hip/hip_runtime.h>

#define NBATCH 8
#define NROWS 2048
#define MDIM 128
#define NITER 50
#define PSTR2 33    // Q^T staging stride (f32), 32 rows + 1
#define RSTR_R 136  // rhs limb row stride (bf16)
#define WLSTR 104   // W-l LDS row stride (bf16), holds k=32..127
#define XSTR 132    // f32 overlay stride (xb / coeff)

// LDS byte offsets (loop layout): 3 rhs limb arrays (32 rows) + W-l + counts
#define RH_B 0
#define RM_B 8704
#define RL_B 17408
#define WL_B 26112      // 128*104*2 = 26624 -> ends 52736
#define CNT_B 52736     // 16*32*4 = 2048 -> 54784
#define SMEM_BYTES 54784
// prologue overlays: pmat (32x128 f64 = 32768) at 0; QST at 32768 (128*33*4=16896)
#define PMAT_B 0
#define QST_B 32768
// epilogue overlays: xbm 32x132x4=16896 at 0; cf at 16896
#define XB_B 0
#define CF_B 16896

typedef unsigned short ushort_t;
typedef __attribute__((ext_vector_type(8))) short bf16x8;
typedef __attribute__((ext_vector_type(8))) unsigned short us8;
typedef __attribute__((ext_vector_type(4))) unsigned short us4;
typedef __attribute__((ext_vector_type(4))) float f32x4;

__device__ __host__ __forceinline__ ushort_t f2bf(float f) {
  unsigned int u = __builtin_bit_cast(unsigned int, f);
  unsigned int r = (u + 0x7fffu + ((u >> 16) & 1u)) >> 16;
  return (ushort_t)r;
}
__device__ __forceinline__ float bf2f(ushort_t h) {
  unsigned int u = ((unsigned int)h) << 16;
  return __builtin_bit_cast(float, u);
}

// ---------------------------------------------------------------------------
// mk_m64: M = I + 2*Vs*Vs^T (f64), X0 = 2I - M.
// grid 256 = 8b x 32 (16x32 tiles). Per-element fma chain identical to R2-R7.
// ---------------------------------------------------------------------------
__global__ __launch_bounds__(256) void mk_m64(const float* __restrict__ V,
                                              double* __restrict__ M,
                                              double* __restrict__ X0) {
  __shared__ double sA[16][130];
  __shared__ double sB[32][130];
  const int b = blockIdx.x >> 5, t = blockIdx.x & 31;
  const int i0 = (t >> 2) << 4, j0 = (t & 3) << 5;
  const float* Vb = V + b * MDIM * MDIM;
  const int tid = threadIdx.x;
  const double S = 1.0 / 128.0;
  for (int idx = tid; idx < 512; idx += 256) {
    const int r = idx >> 5, c4 = (idx & 31) << 2;
    float4 v = *(const float4*)(Vb + (i0 + r) * MDIM + c4);
    sA[r][c4 + 0] = v.x * S; sA[r][c4 + 1] = v.y * S;
    sA[r][c4 + 2] = v.z * S; sA[r][c4 + 3] = v.w * S;
  }
  for (int idx = tid; idx < 1024; idx += 256) {
    const int r = idx >> 5, c4 = (idx & 31) << 2;
    float4 w = *(const float4*)(Vb + (j0 + r) * MDIM + c4);
    sB[r][c4 + 0] = w.x * S; sB[r][c4 + 1] = w.y * S;
    sB[r][c4 + 2] = w.z * S; sB[r][c4 + 3] = w.w * S;
  }
  __syncthreads();
  const int tx = tid & 15, ty = tid >> 4;
  double acc0 = 0.0, acc1 = 0.0;
  for (int k = 0; k < 128; ++k) {
    const double a0 = sA[ty][k];
    const double b0 = sB[tx * 2 + 0][k], b1 = sB[tx * 2 + 1][k];
    acc0 = fma(a0, b0, acc0); acc1 = fma(a0, b1, acc1);
  }
  double* Mb = M + b * 16384;
  double* Xb = X0 + b * 16384;
#pragma unroll
  for (int j = 0; j < 2; ++j) {
    const int gi = i0 + ty, gj = j0 + tx * 2 + j;
    const double diag = (gi == gj) ? 1.0 : 0.0;
    const double mv = 2.0 * (j ? acc1 : acc0) + diag;
    Mb[gi * 128 + gj] = mv;
    Xb[gi * 128 + gj] = 2.0 * diag - mv;
  }
}

// ---------------------------------------------------------------------------
// ns_gemm64: C = A*B (B symmetric, read rows). mode1: C = 2*Xc - A*B.
// grid 256 = 8b x 32 (16x32 tiles). Per-element fma chain identical to R2-R7.
// ---------------------------------------------------------------------------
__global__ __launch_bounds__(256) void ns_gemm64(const double* __restrict__ A,
                                                 const double* __restrict__ B,
                                                 double* __restrict__ C,
                                                 const double* __restrict__ Xc,
                                                 int mode) {
  __shared__ double sA[16][130];
  __shared__ double sB[32][130];
  const int b = blockIdx.x >> 5, t = blockIdx.x & 31;
  const int i0 = (t >> 2) << 4, j0 = (t & 3) << 5;
  const double* Ab = A + b * 16384;
  const double* Bb = B + b * 16384;
  const int tid = threadIdx.x;
  for (int idx = tid; idx < 1024; idx += 256) {
    const int r = idx >> 6, c2 = (idx & 63) << 1;
    *(double2*)&sA[r][c2] = *(const double2*)(Ab + (i0 + r) * 128 + c2);
  }
  for (int idx = tid; idx < 2048; idx += 256) {
    const int r = idx >> 6, c2 = (idx & 63) << 1;
    *(double2*)&sB[r][c2] = *(const double2*)(Bb + (j0 + r) * 128 + c2);
  }
  __syncthreads();
  const int tx = tid & 15, ty = tid >> 4;
  double acc0 = 0.0, acc1 = 0.0;
  for (int k = 0; k < 128; ++k) {
    const double a0 = sA[ty][k];
    const double b0 = sB[tx * 2 + 0][k], b1 = sB[tx * 2 + 1][k];
    acc0 = fma(a0, b0, acc0); acc1 = fma(a0, b1, acc1);
  }
  double* Cb = C + b * 16384;
  const double* Xcb = Xc + b * 16384;
#pragma unroll
  for (int j = 0; j < 2; ++j) {
    const int gi = i0 + ty, gj = j0 + tx * 2 + j;
    double v = (j ? acc1 : acc0);
    if (mode != 0) v = 2.0 * Xcb[gi * 128 + gj] - v;
    Cb[gi * 128 + gj] = v;
  }
}

// ---------------------------------------------------------------------------
// prep_aux: bf16 limb split of W^T (W = I - Minv; exact 3-way split of fp32 W),
// stored transposed Wxg[c*128 + j]; VsT64[d][m] = f64 V[m][d]/128. (unchanged)
// ---------------------------------------------------------------------------
__global__ __launch_bounds__(256) void prep_aux(const double* __restrict__ Minv,
                                                const float* __restrict__ V,
                                                ushort_t* __restrict__ Whg,
                                                ushort_t* __restrict__ Wmg,
                                                ushort_t* __restrict__ Wlg,
                                                double* __restrict__ VsT64) {
  const int b = blockIdx.x >> 3, ch = blockIdx.x & 7;
  const double* Mb = Minv + b * 16384;
  const float* Vb = V + b * 16384;
  ushort_t* Whb = Whg + b * 16384;
  ushort_t* Wmb = Wmg + b * 16384;
  ushort_t* Wlb = Wlg + b * 16384;
  double* Tb = VsT64 + b * 16384;
  const int base = ch * 2048;
  for (int k = threadIdx.x; k < 2048; k += 256) {
    const int idx = base + k;
    const int j = idx >> 7, c = idx & 127;
    const double diag = (j == c) ? 1.0 : 0.0;
    const float wf = (float)(diag - Mb[idx]);
    const ushort_t h = f2bf(wf);
    const float r1 = wf - bf2f(h);
    const ushort_t m_ = f2bf(r1);
    const float r2 = r1 - bf2f(m_);
    const ushort_t l_ = f2bf(r2);
    Whb[c * 128 + j] = h;
    Wmb[c * 128 + j] = m_;
    Wlb[c * 128 + j] = l_;
    Tb[idx] = (double)Vb[c * 128 + j] * (1.0 / 128.0);
  }
}

// ---------------------------------------------------------------------------
// admm_mfma: persistent ADMM, f64 state + exact-split bf16 MFMA correction.
// R8: 512 threads (8 waves), grid 512 -> 2 blocks/CU (convoy overlap);
//     W-h/W-m A-frags fully VGPR-resident; W-l ks0 resident, ks1-3 from LDS.
// Block covers 32 n-rows. Wave w = ct (c-tile); n-tiles nrow0=col16, nrow1=16+col16.
// All per-element fma/MFMA chains identical to R7 -> bit-identical trajectory.
// ---------------------------------------------------------------------------
__global__ __launch_bounds__(512, 4) void admm_mfma(const float* __restrict__ Q,
                                                    const float* __restrict__ V,
                                                    const ushort_t* __restrict__ Whg,
                                                    const ushort_t* __restrict__ Wmg,
                                                    const ushort_t* __restrict__ Wlg,
                                                    const double* __restrict__ VsT64,
                                                    float* __restrict__ out) {
  __shared__ __align__(16) char smem[SMEM_BYTES];
  const int tid = threadIdx.x;
  const int b = blockIdx.x & 7;            // XCD id
  const int n0 = (blockIdx.x >> 3) << 5;   // 32-row tile
  const int lane = tid & 63;
  const int w = tid >> 6;                  // 0..7 = ct
  const int quad = lane >> 4, col16 = lane & 15;
  const int rowA = w * 16 + col16;         // A-frag m-index (c-dim)
  const int nrow0 = col16;                 // B-frag n-index, tile 0
  const int nrow1 = 16 + col16;            // tile 1
  const int cbase = w * 16 + quad * 4;     // C row base (c-dim)
  const int row = lane & 31;               // row mapping for P/epilogue
  const int chalf = lane >> 5;             // col-octet half select

  const float* Qb = Q + ((size_t)(b * NROWS + n0)) * MDIM;
  const float* Vw = V + b * 16384 + w * 16;           // wave-uniform
  const double* vtb = VsT64 + b * 16384 + w * 16;     // wave-uniform
  float* outb = out + ((size_t)(b * NROWS + n0)) * MDIM;
  const ushort_t* WG0 = Whg + b * 16384;
  const ushort_t* WG1 = Wmg + b * 16384;
  const ushort_t* WG2 = Wlg + b * 16384;

  float* QST = (float*)(smem + QST_B);
  double* pmat = (double*)(smem + PMAT_B);
  ushort_t* rhp = (ushort_t*)(smem + RH_B);
  ushort_t* rmp = (ushort_t*)(smem + RM_B);
  ushort_t* rlp = (ushort_t*)(smem + RL_B);
  ushort_t* wl = (ushort_t*)(smem + WL_B);
  float* sCnt = (float*)(smem + CNT_B);

  // ---- Phase 1: stage Q^T (f32): QST[d*33 + r], 32 rows
  for (int idx = tid; idx < 1024; idx += 512) {
    const int r = idx >> 5, d4 = (idx & 31) << 2;
    const float4 q = *(const float4*)(Qb + r * 128 + d4);
    QST[(d4 + 0) * PSTR2 + r] = q.x;
    QST[(d4 + 1) * PSTR2 + r] = q.y;
    QST[(d4 + 2) * PSTR2 + r] = q.z;
    QST[(d4 + 3) * PSTR2 + r] = q.w;
  }
  __syncthreads();

  // ---- Phase 2: P = -2 Q Vs^T + lam/m (f64, d-ascending chain = R7 bits)
  // cols for this thread: w*16 + chalf*8 + i ; vt values via uniform s_loads + select
  double p8[8];
#pragma unroll
  for (int c = 0; c < 8; ++c) p8[c] = 0.0;
  for (int d = 0; d < 128; ++d) {
    const double a = (double)QST[d * PSTR2 + row];
    const double* vt = vtb + d * 128;   // wave-uniform base
#pragma unroll
    for (int c = 0; c < 8; ++c) {
      const double vv = chalf ? vt[8 + c] : vt[c];
      p8[c] = fma(a, vv, p8[c]);
    }
  }
  const double LAM = 0.1 / 128.0;
#pragma unroll
  for (int c = 0; c < 8; ++c) p8[c] = fma(-2.0, p8[c], LAM);
  // pmat region (0..32768) disjoint from QST region -> no barrier needed
#pragma unroll
  for (int c = 0; c < 8; ++c) pmat[row * 128 + w * 16 + chalf * 8 + c] = p8[c];
  __syncthreads();

  // ---- Phase 3: P into MFMA C-layout positions
  double pC[2][4];
#pragma unroll
  for (int i = 0; i < 4; ++i) {
    pC[0][i] = pmat[nrow0 * 128 + cbase + i];
    pC[1][i] = pmat[nrow1 * 128 + cbase + i];
  }
  __syncthreads();  // pmat + QST dead

  // ---- Phase 4: W-l limbs k=32..127 -> LDS; resident A-frags -> VGPRs
  for (int idx = tid; idx < 1536; idx += 512) {
    const int c = idx / 12, t8 = idx - c * 12;
    *(us8*)(wl + c * WLSTR + t8 * 8) = *(const us8*)(WG2 + c * 128 + 32 + t8 * 8);
  }
  bf16x8 wfh[4], wfm[4];
#pragma unroll
  for (int ks = 0; ks < 4; ++ks) {
    wfh[ks] = *(const bf16x8*)(WG0 + rowA * 128 + ks * 32 + quad * 8);
    wfm[ks] = *(const bf16x8*)(WG1 + rowA * 128 + ks * 32 + quad * 8);
  }
  const bf16x8 wf0l = *(const bf16x8*)(WG2 + rowA * 128 + quad * 8);
  __syncthreads();

  // ---- ADMM loop
  double z[2][4], u[2][4];
#pragma unroll
  for (int t = 0; t < 2; ++t)
#pragma unroll
    for (int i = 0; i < 4; ++i) { z[t][i] = 0.0; u[t][i] = 0.0; }

  for (int it = 0; it < NITER; ++it) {
    // split r -> 3 bf16 limbs -> LDS (b64 each)
#pragma unroll
    for (int t = 0; t < 2; ++t) {
      const int nr = t ? nrow1 : nrow0;
      us4 hh, mm2, ll;
#pragma unroll
      for (int i = 0; i < 4; ++i) {
        const double rv = (z[t][i] - u[t][i]) - pC[t][i];
        const float rf = (float)rv;
        const ushort_t h = f2bf(rf);
        const float r1 = rf - bf2f(h);
        const ushort_t m_ = f2bf(r1);
        const float r2 = r1 - bf2f(m_);
        const ushort_t l_ = f2bf(r2);
        hh[i] = h; mm2[i] = m_; ll[i] = l_;
      }
      *(us4*)(rhp + nr * RSTR_R + cbase) = hh;
      *(us4*)(rmp + nr * RSTR_R + cbase) = mm2;
      *(us4*)(rlp + nr * RSTR_R + cbase) = ll;
    }
    __syncthreads();

    f32x4 acc0 = {0.f, 0.f, 0.f, 0.f};
    f32x4 acc1 = {0.f, 0.f, 0.f, 0.f};
#pragma unroll
    for (int ks = 0; ks < 4; ++ks) {
      const bf16x8 ah = wfh[ks];
      const bf16x8 am2 = wfm[ks];
      const bf16x8 al2 = (ks == 0)
          ? wf0l
          : *(const bf16x8*)(wl + rowA * WLSTR + (ks - 1) * 32 + quad * 8);
      const int kq = ks * 32 + quad * 8;
      {  // tile 0
        const bf16x8 bh = *(const bf16x8*)(rhp + nrow0 * RSTR_R + kq);
        const bf16x8 bm = *(const bf16x8*)(rmp + nrow0 * RSTR_R + kq);
        const bf16x8 bl = *(const bf16x8*)(rlp + nrow0 * RSTR_R + kq);
        acc0 = __builtin_amdgcn_mfma_f32_16x16x32_bf16(ah,  bh, acc0, 0, 0, 0);
        acc0 = __builtin_amdgcn_mfma_f32_16x16x32_bf16(ah,  bm, acc0, 0, 0, 0);
        acc0 = __builtin_amdgcn_mfma_f32_16x16x32_bf16(am2, bh, acc0, 0, 0, 0);
        acc0 = __builtin_amdgcn_mfma_f32_16x16x32_bf16(am2, bm, acc0, 0, 0, 0);
        acc0 = __builtin_amdgcn_mfma_f32_16x16x32_bf16(ah,  bl, acc0, 0, 0, 0);
        acc0 = __builtin_amdgcn_mfma_f32_16x16x32_bf16(al2, bh, acc0, 0, 0, 0);
      }
      {  // tile 1
        const bf16x8 bh = *(const bf16x8*)(rhp + nrow1 * RSTR_R + kq);
        const bf16x8 bm = *(const bf16x8*)(rmp + nrow1 * RSTR_R + kq);
        const bf16x8 bl = *(const bf16x8*)(rlp + nrow1 * RSTR_R + kq);
        acc1 = __builtin_amdgcn_mfma_f32_16x16x32_bf16(ah,  bh, acc1, 0, 0, 0);
        acc1 = __builtin_amdgcn_mfma_f32_16x16x32_bf16(ah,  bm, acc1, 0, 0, 0);
        acc1 = __builtin_amdgcn_mfma_f32_16x16x32_bf16(am2, bh, acc1, 0, 0, 0);
        acc1 = __builtin_amdgcn_mfma_f32_16x16x32_bf16(am2, bm, acc1, 0, 0, 0);
        acc1 = __builtin_amdgcn_mfma_f32_16x16x32_bf16(ah,  bl, acc1, 0, 0, 0);
        acc1 = __builtin_amdgcn_mfma_f32_16x16x32_bf16(al2, bh, acc1, 0, 0, 0);
      }
    }
    __syncthreads();  // all rhs reads done before next iteration's writes

#pragma unroll
    for (int t = 0; t < 2; ++t)
#pragma unroll
      for (int i = 0; i < 4; ++i) {
        const float corr = (t == 0) ? acc0[i] : acc1[i];
        const double rv = (z[t][i] - u[t][i]) - pC[t][i];  // recompute (bit-identical)
        const double x = rv - (double)corr;
        const double y = x + u[t][i];
        const double zn = fmin(fmax(y, 0.0), 1.0);
        u[t][i] = y - zn;
        z[t][i] = zn;
      }
  }

  // ---- epilogue: threshold in C-layout, xb -> LDS matrix
  float* xbm = (float*)(smem + XB_B);
#pragma unroll
  for (int t = 0; t < 2; ++t) {
    const int nr = t ? nrow1 : nrow0;
    float4 o;
    o.x = (z[t][0] > 0.5) ? 1.f : 0.f;
    o.y = (z[t][1] > 0.5) ? 1.f : 0.f;
    o.z = (z[t][2] > 0.5) ? 1.f : 0.f;
    o.w = (z[t][3] > 0.5) ? 1.f : 0.f;
    *(float4*)(xbm + nr * XSTR + cbase) = o;
  }
  __syncthreads();

  // ---- row-mapping epilogue: counts, coeffs, out = coeffs . V
  const int c8 = w * 16 + chalf * 8;  // this thread's col-octet
  float xb8[8];
  {
    const float4 a = *(const float4*)(xbm + row * XSTR + c8 + 0);
    const float4 c2 = *(const float4*)(xbm + row * XSTR + c8 + 4);
    xb8[0] = a.x; xb8[1] = a.y; xb8[2] = a.z; xb8[3] = a.w;
    xb8[4] = c2.x; xb8[5] = c2.y; xb8[6] = c2.z; xb8[7] = c2.w;
  }
  double cnt = 0.0;
#pragma unroll
  for (int c = 0; c < 8; ++c) cnt += (double)xb8[c];
  sCnt[(w * 2 + chalf) * 32 + row] = (float)cnt;
  __syncthreads();
  double k = 0.0;
#pragma unroll
  for (int g = 0; g < 16; ++g) k += (double)sCnt[g * 32 + row];
  const double rkS = (1.0 / 128.0) / (k + 1e-10);
  float* cf = (float*)(smem + CF_B);
  {
    float4 w0, w1;
    w0.x = (float)((double)xb8[0] * rkS); w0.y = (float)((double)xb8[1] * rkS);
    w0.z = (float)((double)xb8[2] * rkS); w0.w = (float)((double)xb8[3] * rkS);
    w1.x = (float)((double)xb8[4] * rkS); w1.y = (float)((double)xb8[5] * rkS);
    w1.z = (float)((double)xb8[6] * rkS); w1.w = (float)((double)xb8[7] * rkS);
    *(float4*)(cf + row * XSTR + c8 + 0) = w0;
    *(float4*)(cf + row * XSTR + c8 + 4) = w1;
  }
  __syncthreads();

  // out GEMM, m-ascending chain; V values via uniform s_loads + half-select
  float oa[8];
#pragma unroll
  for (int c = 0; c < 8; ++c) oa[c] = 0.f;
#pragma unroll 4
  for (int m4 = 0; m4 < 32; ++m4) {
    const float4 a4 = *(const float4*)(cf + row * XSTR + (m4 << 2));
#pragma unroll
    for (int mm = 0; mm < 4; ++mm) {
      const int m = (m4 << 2) + mm;
      const float* vp = Vw + m * 128;   // wave-uniform
      const float am = (mm == 0) ? a4.x : (mm == 1) ? a4.y : (mm == 2) ? a4.z : a4.w;
#pragma unroll
      for (int c = 0; c < 8; ++c) {
        const float vv = chalf ? vp[8 + c] : vp[c];
        oa[c] = fmaf(am, vv, oa[c]);
      }
    }
  }
#pragma unroll
  for (int q = 0; q < 2; ++q) {
    float4 o;
    o.x = oa[q * 4 + 0]; o.y = oa[q * 4 + 1];
    o.z = oa[q * 4 + 2]; o.w = oa[q * 4 + 3];
    *(float4*)(outb + row * 128 + c8 + q * 4) = o;
  }
}

// ---------------------------------------------------------------------------
extern "C" void kernel_launch(void* const* d_in, const int* in_sizes, int n_in,
                              void* d_out, int out_size, void* d_ws, size_t ws_size,
                              hipStream_t stream) {
  const float* Q = (const float*)d_in[0];
  const float* V = (const float*)d_in[1];
  float* out = (float*)d_out;
  double* ws = (double*)d_ws;
  double* Mw = ws;                // 1 MiB: M; recycled as bf16 W-limb arrays
  double* Xa = ws + 131072;
  double* Xb = ws + 262144;
  double* Tw = ws + 393216;       // NS temp; recycled as VsT64

  mk_m64<<<256, 256, 0, stream>>>(V, Mw, Xa);
  double* pa = Xa;
  double* pb = Xb;
  for (int i = 0; i < 3; ++i) {  // Newton-Schulz f64: residual ~6e-20
    ns_gemm64<<<256, 256, 0, stream>>>(pa, Mw, Tw, pa, 0);  // T = X*M
    ns_gemm64<<<256, 256, 0, stream>>>(Tw, pa, pb, pa, 1);  // X' = 2X - T*X
    double* tmp = pa; pa = pb; pb = tmp;
  }
  ushort_t* Whg = (ushort_t*)Mw;
  ushort_t* Wmg = Whg + 131072;
  ushort_t* Wlg = Whg + 262144;
  double* VsT64 = Tw;
  prep_aux<<<64, 256, 0, stream>>>(pa, V, Whg, Wmg, Wlg, VsT64);
  admm_mfma<<<512, 512, 0, stream>>>(Q, V, Whg, Wmg, Wlg, VsT64, out);
}